// Round 3
// baseline (116.513 us; speedup 1.0000x reference)
//
#include <hip/hip_runtime.h>
#include <hip/hip_bf16.h>

// Problem constants (B=1). All inputs/outputs are float32.
#define HH   96
#define WW   96
#define NPIX 9216          // 96*96
#define CH   128
#define NH   8
#define HD   16
#define KS   8

#define NEPIX   2304       // 48*48 even-even grid (k/v only ever read there)
#define NPOS    120        // 8 window rows x 15 window cols per 16-px segment
#define QTPITCH 136        // conv q-tile pitch (ch)
#define KVTPITCH 264       // conv kv-tile pitch (ch, k+v = 256 + pad)
#define XPITCH  97         // conv input-slab pitch (floats per channel)
#define KVP2    136        // fused attn LDS pitch: 128 ch + 8 pad (ushort)
#define AOPITCH 132        // attn-out LDS pitch (floats, 16B aligned)

__device__ __forceinline__ unsigned short f2bf(float f) {
    __hip_bfloat16 b = __float2bfloat16(f);
    union { __hip_bfloat16 b; unsigned short u; } cv; cv.b = b; return cv.u;
}
// unpack uint4 = 8 bf16 -> 8 fp32
__device__ __forceinline__ void u4_to_f8(uint4 u, float* f) {
    f[0] = __uint_as_float(u.x << 16); f[1] = __uint_as_float(u.x & 0xffff0000u);
    f[2] = __uint_as_float(u.y << 16); f[3] = __uint_as_float(u.y & 0xffff0000u);
    f[4] = __uint_as_float(u.z << 16); f[5] = __uint_as_float(u.z & 0xffff0000u);
    f[6] = __uint_as_float(u.w << 16); f[7] = __uint_as_float(u.w & 0xffff0000u);
}

// ---------------------------------------------------------------------------
// K1: depthwise 3x3 conv (unchanged from round 1 — measured equal to R0).
// q at ALL pixels -> q_pm [NPIX][CH]; k/v ONLY at even-even pixels ->
// compact kv_pm [2][NEPIX][CH].
// ---------------------------------------------------------------------------
__global__ __launch_bounds__(256) void conv_kernel(
    const float* __restrict__ x,        // [128][96][96]
    const float* __restrict__ w,        // [384][1][3][3]
    const float* __restrict__ bias,     // [384]
    unsigned short* __restrict__ q_pm,  // [NPIX][CH] bf16
    unsigned short* __restrict__ kv_pm) // [2][NEPIX][CH] bf16
{
    __shared__ float ldsx[128 * XPITCH];            // 49,664 B
    __shared__ unsigned short qt [24 * QTPITCH];    // 6,528 B
    __shared__ unsigned short kvt[12 * KVTPITCH];   // 6,336 B

    const int row = blockIdx.x >> 2;    // 0..95
    const int qtr = blockIdx.x & 3;     // 0..3
    const int j0q = qtr * 24;
    const int tid = threadIdx.x;
    const int g   = tid >> 1;           // 0..127 input channel / group
    const int sh  = tid & 1;            // 0/1 -> 12 px each
    const bool kvrow = (row & 1) == 0;  // block-uniform

    // ---- stage x[c][row-1..row+1][j0q-4..j0q+27] -> LDS, coalesced ----
    #pragma unroll
    for (int it = 0; it < 12; ++it) {
        const int t  = it * 256 + tid;      // 0..3071
        const int r  = t >> 10;             // 0..2
        const int c  = (t >> 3) & 127;      // 0..127
        const int s4 = t & 7;               // 0..7
        const int rg = row + r - 1;
        const int j  = j0q - 4 + s4 * 4;    // 4-aligned; fully in or out
        float4 v = make_float4(0.f, 0.f, 0.f, 0.f);
        if (rg >= 0 && rg < HH && j >= 0 && j < WW)
            v = *(const float4*)(x + (size_t)c * NPIX + rg * WW + j);
        *(float4*)&ldsx[c * XPITCH + r * 32 + s4 * 4] = v;
    }
    __syncthreads();

    float xr[3][14];
    {
        const float* xg_l = &ldsx[g * XPITCH + 3 + sh * 12];
        #pragma unroll
        for (int dr = 0; dr < 3; ++dr)
            #pragma unroll
            for (int m = 0; m < 14; ++m)
                xr[dr][m] = xg_l[dr * 32 + m];
    }

    #pragma unroll
    for (int dt = 0; dt < 3; ++dt) {
        const int o = 3 * g + dt;       // conv out-channel (group g)
        const int t = o >> 7;           // 0=q, 1=k, 2=v
        const int c = o & 127;
        float w9[9];
        #pragma unroll
        for (int k = 0; k < 9; ++k) w9[k] = w[o * 9 + k];
        const float b = bias[o];

        if (t == 0) {
            #pragma unroll
            for (int px = 0; px < 12; ++px) {
                float acc = b;
                #pragma unroll
                for (int kh = 0; kh < 3; ++kh)
                    #pragma unroll
                    for (int kw = 0; kw < 3; ++kw)
                        acc += xr[kh][px + kw] * w9[kh * 3 + kw];
                qt[(sh * 12 + px) * QTPITCH + c] = f2bf(acc);
            }
        } else if (kvrow) {
            #pragma unroll
            for (int pe = 0; pe < 6; ++pe) {        // even px only
                const int px = pe * 2;
                float acc = b;
                #pragma unroll
                for (int kh = 0; kh < 3; ++kh)
                    #pragma unroll
                    for (int kw = 0; kw < 3; ++kw)
                        acc += xr[kh][px + kw] * w9[kh * 3 + kw];
                kvt[(sh * 6 + pe) * KVTPITCH + (t - 1) * CH + c] = f2bf(acc);
            }
        }
    }

    __syncthreads();

    const int ntask = kvrow ? 768 : 384;
    #pragma unroll
    for (int it = 0; it < 3; ++it) {
        const int idx = it * 256 + tid;
        if (idx < 384) {
            const int px  = idx >> 4;           // 0..23
            const int c8  = (idx & 15) * 8;
            const uint4 v = *(const uint4*)&qt[px * QTPITCH + c8];
            *(uint4*)(q_pm + ((size_t)(row * WW) + j0q + px) * CH + c8) = v;
        } else if (idx < ntask) {
            const int k2  = idx - 384;
            const int epx = k2 >> 5;            // 0..11
            const int c32 = (k2 & 31) * 8;      // 0..255 ch (k then v)
            const int t1  = c32 >> 7;           // 0=k, 1=v
            const int c   = c32 & 127;
            const uint4 v = *(const uint4*)&kvt[epx * KVTPITCH + c32];
            *(uint4*)(kv_pm + ((size_t)t1 * NEPIX + (row >> 1) * 48
                               + (j0q >> 1) + epx) * CH + c) = v;
        }
    }
}

// ---------------------------------------------------------------------------
// K2 (NEW): fused neighborhood attention + 1x1 projection.
// One block per 16-px segment; 1024 thr = 4x the R12-proven 256-thr attn
// group (hp = tid>>8 replaces blockIdx.y; lane = tid&63 keeps the same
// (r,hh,px) layout so the __shfl_xor merge is unchanged). K,V staged for
// ALL heads: kv[2][120 pos][136 ch] bf16 (65.3 KB). Attention output goes
// to LDS ao[16 px][132 ch] f32 (8.4 KB) instead of global a_t; the proj
// phase (2 out-ch per thread, fp32 accum) writes `out` directly.
// Eliminates: one kernel launch + the 9.4 MB a_t global round-trip.
// LDS 72 KB -> 1 block/CU (16 waves). Grid 576.
// ---------------------------------------------------------------------------
__global__ __launch_bounds__(1024) void attnproj_kernel(
    const unsigned short* __restrict__ q_pm,    // [NPIX][CH] bf16
    const unsigned short* __restrict__ kv_pm,   // [2][NEPIX][CH] bf16
    const float* __restrict__ pw,               // [128][128] ([o][c])
    const float* __restrict__ pb,               // [128]
    float* __restrict__ out)                    // [128][NPIX]
{
    __shared__ unsigned short kv[2][NPOS][KVP2];    // 65,280 B
    __shared__ float ao[16][AOPITCH];               // 8,448 B

    const int tid = threadIdx.x;
    const int seg = blockIdx.x;                 // 0..575
    const int i   = seg / 6;                    // image row
    const int j0  = (seg - i * 6) * 16;
    const int rs     = 2 * min(max(i / 2 - 3, 0), 40);
    const int cs_min = 2 * min(max(j0 / 2 - 3, 0), 40);
    const int er0 = rs >> 1;                    // compact window row base
    const int ec0 = cs_min >> 1;                // compact window col base

    // ---- stage K,V (all heads): 3840 uint4 tasks ----
    #pragma unroll
    for (int it = 0; it < 4; ++it) {
        const int idx = it * 1024 + tid;
        if (idx < 3840) {
            const int kvsel = idx / 1920;
            const int rem   = idx - kvsel * 1920;
            const int pos   = rem >> 4;             // 0..119
            const int c8    = rem & 15;             // 0..15 (8-ch chunks)
            const int p     = pos / 15;
            const int cc    = pos - p * 15;
            const int ec    = min(ec0 + cc, 47);    // right-edge clamp (unused cols)
            const int ep    = (er0 + p) * 48 + ec;
            *(uint4*)&kv[kvsel][pos][c8 * 8] =
                *(const uint4*)(kv_pm + ((size_t)kvsel * NEPIX + ep) * CH + c8 * 8);
        }
    }

    // ---- per-thread coordinates (hp = tid>>8; rest identical to R12) ----
    const int hp    = tid >> 8;                 // head pair 0..3
    const int t256  = tid & 255;
    const int lane  = t256 & 63;                // == tid & 63 (HW lane)
    const int wv    = t256 >> 6;                // 0..3
    const int r     = lane >> 3;                // window-row split
    const int hh    = (lane >> 2) & 1;          // head within pair
    const int px    = wv * 4 + (lane & 3);      // 0..15
    const int h     = hp * 2 + hh;
    const int pix   = seg * 16 + px;
    const int j     = j0 + px;
    const int ci0   = (2 * min(max(j / 2 - 3, 0), 40) - cs_min) >> 1;  // 0..7

    float qr[HD];
    {
        const unsigned short* qp = q_pm + (size_t)pix * CH + h * HD;
        u4_to_f8(*(const uint4*)qp, qr);
        u4_to_f8(*(const uint4*)(qp + 8), qr + 8);
        #pragma unroll
        for (int d = 0; d < HD; ++d) qr[d] *= 0.25f;   // HD^-0.5
    }

    __syncthreads();

    const int posr = r * 15 + ci0;
    float lg[KS];
    float m = -1e30f;
    #pragma unroll
    for (int q = 0; q < KS; ++q) {
        const unsigned short* kp = &kv[0][posr + q][hp * 32 + hh * HD];
        float kf[HD];
        u4_to_f8(*(const uint4*)kp, kf);
        u4_to_f8(*(const uint4*)(kp + 8), kf + 8);
        float acc = 0.f;
        #pragma unroll
        for (int d = 0; d < HD; ++d) acc += qr[d] * kf[d];
        lg[q] = acc;
        m = fmaxf(m, acc);
    }

    float s = 0.f;
    #pragma unroll
    for (int q = 0; q < KS; ++q) { lg[q] = __expf(lg[q] - m); s += lg[q]; }

    float o[HD];
    #pragma unroll
    for (int d = 0; d < HD; ++d) o[d] = 0.f;
    #pragma unroll
    for (int q = 0; q < KS; ++q) {
        const unsigned short* vp = &kv[1][posr + q][hp * 32 + hh * HD];
        float vf[HD];
        u4_to_f8(*(const uint4*)vp, vf);
        u4_to_f8(*(const uint4*)(vp + 8), vf + 8);
        const float wgt = lg[q];
        #pragma unroll
        for (int d = 0; d < HD; ++d) o[d] += wgt * vf[d];
    }

    #pragma unroll
    for (int mask = 8; mask <= 32; mask <<= 1) {
        const float m2 = __shfl_xor(m, mask);
        const float s2 = __shfl_xor(s, mask);
        const float mn = fmaxf(m, m2);
        const float ea = __expf(m - mn);
        const float eb = __expf(m2 - mn);
        s = s * ea + s2 * eb;
        #pragma unroll
        for (int d = 0; d < HD; ++d) {
            const float o2 = __shfl_xor(o[d], mask);
            o[d] = o[d] * ea + o2 * eb;
        }
        m = mn;
    }
    const float inv = 1.f / s;

    // write this thread's 2 channels to the LDS attn-out tile
    ao[px][h * HD + 2 * r]     = o[2 * r]     * inv;
    ao[px][h * HD + 2 * r + 1] = o[2 * r + 1] * inv;

    __syncthreads();

    // ---- proj phase: out[o][seg*16+px] = pb[o] + sum_c pw[o][c]*ao[px][c]
    // thread -> (2 out-ch, 1 px): og = tid>>4 (16-lane broadcast of pw rows),
    // ppx = tid&15 (64B-coalesced stores).
    const int og  = tid >> 4;               // 0..63
    const int o0  = og * 2;
    const int ppx = tid & 15;

    float acc0 = pb[o0];
    float acc1 = pb[o0 + 1];
    #pragma unroll 4
    for (int c0 = 0; c0 < CH; c0 += 4) {
        const float4 av = *(const float4*)&ao[ppx][c0];
        const float4 w0 = *(const float4*)(pw + (size_t)o0 * CH + c0);
        const float4 w1 = *(const float4*)(pw + (size_t)(o0 + 1) * CH + c0);
        acc0 += av.x * w0.x; acc0 += av.y * w0.y;
        acc0 += av.z * w0.z; acc0 += av.w * w0.w;
        acc1 += av.x * w1.x; acc1 += av.y * w1.y;
        acc1 += av.z * w1.z; acc1 += av.w * w1.w;
    }

    const int pxg = seg * 16 + ppx;
    out[(size_t)o0 * NPIX + pxg]       = acc0;
    out[(size_t)(o0 + 1) * NPIX + pxg] = acc1;
}

// ---------------------------------------------------------------------------
extern "C" void kernel_launch(void* const* d_in, const int* in_sizes, int n_in,
                              void* d_out, int out_size, void* d_ws, size_t ws_size,
                              hipStream_t stream)
{
    const float* x      = (const float*)d_in[0];
    const float* qkv_w  = (const float*)d_in[1];
    const float* qkv_b  = (const float*)d_in[2];
    const float* proj_w = (const float*)d_in[3];
    const float* proj_b = (const float*)d_in[4];
    float* out = (float*)d_out;

    // ws: [q_pm 2.36 MB][kv_pm 1.18 MB]
    unsigned short* q_pm  = (unsigned short*)d_ws;             // [NPIX][CH]
    unsigned short* kv_pm = q_pm + (size_t)NPIX * CH;          // [2][NEPIX][CH]

    conv_kernel<<<384, 256, 0, stream>>>(x, qkv_w, qkv_b, q_pm, kv_pm);
    attnproj_kernel<<<576, 1024, 0, stream>>>(q_pm, kv_pm, proj_w, proj_b, out);
}

// Round 4
// 95.925 us; speedup vs baseline: 1.2146x; 1.2146x over previous
//
#include <hip/hip_runtime.h>
#include <hip/hip_bf16.h>

// Problem constants (B=1). All inputs/outputs are float32.
#define HH   96
#define WW   96
#define NPIX 9216          // 96*96
#define CH   128
#define NH   8
#define HD   16
#define KS   8

#define NEPIX   2304       // 48*48 even-even grid (k/v only ever read there)
#define QTPITCH 136        // conv q-tile pitch (ch)
#define KVTPITCH 264       // conv kv-tile pitch (ch, k+v = 256 + pad)
#define XPITCH  97         // conv input-slab pitch (floats per channel)
#define PPITCH  280        // attn P-lds pitch (ush): hi at 0..127, lo at 136..263

typedef __attribute__((ext_vector_type(8))) short bf16x8;
typedef __attribute__((ext_vector_type(4))) float f32x4;

__device__ __forceinline__ unsigned short f2bf(float f) {
    __hip_bfloat16 b = __float2bfloat16(f);
    union { __hip_bfloat16 b; unsigned short u; } cv; cv.b = b; return cv.u;
}
__device__ __forceinline__ bf16x8 u4_as_bf(uint4 u) {
    union { uint4 u; bf16x8 b; } cv; cv.u = u; return cv.b;
}

// ---------------------------------------------------------------------------
// K1: depthwise 3x3 conv. q at ALL pixels -> q_pm [NPIX][CH]; k ONLY at
// even-even pixels -> k_pm [NEPIX][CH]; v at even-even pixels TRANSPOSED ->
// vt_pm [CH][NEPIX] (bf16) so attn can read V^T MFMA fragments contiguously.
// Conv math per-output identical to the proven kernel.
// ---------------------------------------------------------------------------
__global__ __launch_bounds__(256) void conv_kernel(
    const float* __restrict__ x,        // [128][96][96]
    const float* __restrict__ w,        // [384][1][3][3]
    const float* __restrict__ bias,     // [384]
    unsigned short* __restrict__ q_pm,  // [NPIX][CH] bf16
    unsigned short* __restrict__ k_pm,  // [NEPIX][CH] bf16
    unsigned short* __restrict__ vt_pm) // [CH][NEPIX] bf16
{
    __shared__ float ldsx[128 * XPITCH];            // 49,664 B
    __shared__ unsigned short qt [24 * QTPITCH];    // 6,528 B
    __shared__ unsigned short kvt[12 * KVTPITCH];   // 6,336 B

    const int row = blockIdx.x >> 2;    // 0..95
    const int qtr = blockIdx.x & 3;     // 0..3
    const int j0q = qtr * 24;
    const int tid = threadIdx.x;
    const int g   = tid >> 1;           // 0..127 input channel / group
    const int sh  = tid & 1;            // 0/1 -> 12 px each
    const bool kvrow = (row & 1) == 0;  // block-uniform

    // ---- stage x[c][row-1..row+1][j0q-4..j0q+27] -> LDS, coalesced ----
    #pragma unroll
    for (int it = 0; it < 12; ++it) {
        const int t  = it * 256 + tid;      // 0..3071
        const int r  = t >> 10;             // 0..2
        const int c  = (t >> 3) & 127;      // 0..127
        const int s4 = t & 7;               // 0..7
        const int rg = row + r - 1;
        const int jj = j0q - 4 + s4 * 4;    // 4-aligned; fully in or out
        float4 v = make_float4(0.f, 0.f, 0.f, 0.f);
        if (rg >= 0 && rg < HH && jj >= 0 && jj < WW)
            v = *(const float4*)(x + (size_t)c * NPIX + rg * WW + jj);
        *(float4*)&ldsx[c * XPITCH + r * 32 + s4 * 4] = v;
    }
    __syncthreads();

    float xr[3][14];
    {
        const float* xg_l = &ldsx[g * XPITCH + 3 + sh * 12];
        #pragma unroll
        for (int dr = 0; dr < 3; ++dr)
            #pragma unroll
            for (int mm = 0; mm < 14; ++mm)
                xr[dr][mm] = xg_l[dr * 32 + mm];
    }

    #pragma unroll
    for (int dt = 0; dt < 3; ++dt) {
        const int o = 3 * g + dt;       // conv out-channel (group g)
        const int t = o >> 7;           // 0=q, 1=k, 2=v
        const int c = o & 127;
        float w9[9];
        #pragma unroll
        for (int k = 0; k < 9; ++k) w9[k] = w[o * 9 + k];
        const float b = bias[o];

        if (t == 0) {
            #pragma unroll
            for (int px = 0; px < 12; ++px) {
                float acc = b;
                #pragma unroll
                for (int kh = 0; kh < 3; ++kh)
                    #pragma unroll
                    for (int kw = 0; kw < 3; ++kw)
                        acc += xr[kh][px + kw] * w9[kh * 3 + kw];
                qt[(sh * 12 + px) * QTPITCH + c] = f2bf(acc);
            }
        } else if (kvrow) {
            #pragma unroll
            for (int pe = 0; pe < 6; ++pe) {        // even px only
                const int px = pe * 2;
                float acc = b;
                #pragma unroll
                for (int kh = 0; kh < 3; ++kh)
                    #pragma unroll
                    for (int kw = 0; kw < 3; ++kw)
                        acc += xr[kh][px + kw] * w9[kh * 3 + kw];
                kvt[(sh * 6 + pe) * KVTPITCH + (t - 1) * CH + c] = f2bf(acc);
            }
        }
    }

    __syncthreads();

    // write: q 384 tasks; even rows add K 192 tasks + V-transpose 512 slots
    const int ntask = kvrow ? 1088 : 384;
    #pragma unroll
    for (int it = 0; it < 5; ++it) {
        const int idx = it * 256 + tid;
        if (idx < 384) {
            const int px  = idx >> 4;           // 0..23
            const int c8  = (idx & 15) * 8;
            const uint4 v = *(const uint4*)&qt[px * QTPITCH + c8];
            *(uint4*)(q_pm + ((size_t)(row * WW) + j0q + px) * CH + c8) = v;
        } else if (idx < 576 && kvrow) {        // K: 192 uint4 tasks
            const int k2  = idx - 384;
            const int epx = k2 >> 4;            // 0..11
            const int c8  = (k2 & 15) * 8;
            const uint4 v = *(const uint4*)&kvt[epx * KVTPITCH + c8];
            *(uint4*)(k_pm + ((size_t)(row >> 1) * 48 + (j0q >> 1) + epx) * CH + c8) = v;
        } else if (idx < ntask) {               // V transpose: 384 of 512 slots
            const int v2   = idx - 576;
            const int c    = v2 >> 2;           // 0..127
            const int quad = v2 & 3;            // 0..3 (3 = idle)
            if (quad < 3) {
                const int e0 = quad * 4;
                const unsigned short* src = &kvt[CH + c];   // v half
                const unsigned int a0 =
                    (unsigned int)src[(e0 + 0) * KVTPITCH]
                    | ((unsigned int)src[(e0 + 1) * KVTPITCH] << 16);
                const unsigned int a1 =
                    (unsigned int)src[(e0 + 2) * KVTPITCH]
                    | ((unsigned int)src[(e0 + 3) * KVTPITCH] << 16);
                *(uint2*)(vt_pm + (size_t)c * NEPIX + (row >> 1) * 48
                          + (j0q >> 1) + e0) = make_uint2(a0, a1);
            }
        }
    }
}

// ---------------------------------------------------------------------------
// K2 (NEW): MFMA neighborhood attention. Grid 576 segs x 512 thr = 8 waves,
// one wave per head; NO barriers (per-wave-private LDS P region).
// Window = 8 rows x 16 cols (15 used) on the even-even grid.
//  QK^T: 8x mfma_f32_16x16x32_bf16, A=K-window tile (M=cc,K=d zero-padded
//        16->32), B=Q (N=px). D: col=lane&15=px, row=(lane>>4)*4+reg=cc.
//  softmax: mask cc vs per-px ci0; row-reduce = lane-local + shfl_xor 16,32.
//  P split into hi+lo bf16 (f32-accurate) -> per-wave LDS [16px][280] ush.
//  PV: 4 kt x {hi,lo} mfma, A=V^T (direct from vt_pm, funnel-shift for the
//      odd window base), B=P^T from LDS. D: col=px, row=d. Defer 1/s to end.
// LDS 71,680 B -> 2 blocks/CU = 16 waves/CU.
// ---------------------------------------------------------------------------
__global__ __launch_bounds__(512, 4) void attn_kernel(
    const unsigned short* __restrict__ q_pm,    // [NPIX][CH] bf16
    const unsigned short* __restrict__ k_pm,    // [NEPIX][CH] bf16
    const unsigned short* __restrict__ vt_pm,   // [CH][NEPIX] bf16
    float* __restrict__ a_t)                    // [CH][NPIX] fp32
{
    __shared__ unsigned short plds[NH][16 * PPITCH];    // 71,680 B

    const int seg = blockIdx.x;                 // 0..575
    const int i   = seg / 6;                    // image row
    const int j0  = (seg - i * 6) * 16;
    const int er0 = min(max(i / 2 - 3, 0), 40); // compact window row base
    const int ec0 = min(max(j0 / 2 - 3, 0), 40);// compact window col base

    const int tid  = threadIdx.x;
    const int h    = tid >> 6;                  // head = wave
    const int lane = tid & 63;
    const int nn   = lane & 15;                 // px (B/D cols); cc (A rows)
    const int g    = lane >> 4;                 // 0..3

    const int j   = j0 + nn;
    const int ci0 = min(max(j / 2 - 3, 0), 40) - ec0;   // 0..7 (per px)

    // ---- QK^T ----
    bf16x8 qf = (bf16x8)(short)0;
    if (g < 2)
        qf = u4_as_bf(*(const uint4*)(q_pm + (size_t)(seg * 16 + nn) * CH
                                      + h * HD + g * 8));
    const f32x4 zacc = {0.f, 0.f, 0.f, 0.f};
    f32x4 st[8];
    #pragma unroll
    for (int t = 0; t < 8; ++t) {
        bf16x8 kf = (bf16x8)(short)0;
        if (g < 2) {
            const int ep = (er0 + t) * 48 + min(ec0 + nn, 47);
            kf = u4_as_bf(*(const uint4*)(k_pm + (size_t)ep * CH
                                          + h * HD + g * 8));
        }
        st[t] = __builtin_amdgcn_mfma_f32_16x16x32_bf16(kf, qf, zacc, 0, 0, 0);
    }

    // ---- masked softmax (value = S*0.25; invalid -> -1e30) ----
    float m = -1e30f;
    #pragma unroll
    for (int t = 0; t < 8; ++t)
        #pragma unroll
        for (int r = 0; r < 4; ++r) {
            const int cc = g * 4 + r;
            float T = st[t][r] * 0.25f;                 // HD^-0.5
            T = ((unsigned)(cc - ci0) < 8u) ? T : -1e30f;
            st[t][r] = T;
            m = fmaxf(m, T);
        }
    m = fmaxf(m, __shfl_xor(m, 16));
    m = fmaxf(m, __shfl_xor(m, 32));

    float s = 0.f;
    #pragma unroll
    for (int t = 0; t < 8; ++t)
        #pragma unroll
        for (int r = 0; r < 4; ++r) {
            const float p = __expf(st[t][r] - m);       // invalid -> 0
            st[t][r] = p;
            s += p;
        }
    s += __shfl_xor(s, 16);
    s += __shfl_xor(s, 32);

    // ---- pack P = hi + lo bf16, write to per-wave LDS ----
    unsigned short* pl = &plds[h][nn * PPITCH];
    const int g4 = g * 4;
    #pragma unroll
    for (int t = 0; t < 8; ++t) {
        const float p0 = st[t][0], p1 = st[t][1], p2 = st[t][2], p3 = st[t][3];
        const unsigned short h0 = f2bf(p0), h1 = f2bf(p1),
                             h2 = f2bf(p2), h3 = f2bf(p3);
        const float r0 = p0 - __uint_as_float((unsigned)h0 << 16);
        const float r1 = p1 - __uint_as_float((unsigned)h1 << 16);
        const float r2 = p2 - __uint_as_float((unsigned)h2 << 16);
        const float r3 = p3 - __uint_as_float((unsigned)h3 << 16);
        const unsigned short l0 = f2bf(r0), l1 = f2bf(r1),
                             l2 = f2bf(r2), l3 = f2bf(r3);
        *(uint2*)&pl[t * 16 + g4] =
            make_uint2((unsigned)h0 | ((unsigned)h1 << 16),
                       (unsigned)h2 | ((unsigned)h3 << 16));
        *(uint2*)&pl[136 + t * 16 + g4] =
            make_uint2((unsigned)l0 | ((unsigned)l1 << 16),
                       (unsigned)l2 | ((unsigned)l3 << 16));
    }

    // ---- PV: O^T[d][px] += V^T x P^T (hi + lo) ----
    const unsigned short* vbase = vt_pm + (size_t)(h * HD + nn) * NEPIX; // nn=d
    const int ecs = ec0 & ~7;                   // aligned col base
    const int shft = ec0 & 7;                   // 0 or 5 (block-uniform)
    f32x4 acc = {0.f, 0.f, 0.f, 0.f};
    #pragma unroll
    for (int kt = 0; kt < 4; ++kt) {
        const int vrow = er0 + kt * 2 + (g >> 1);
        const int coff = vrow * 48 + ecs + (g & 1) * 8;
        const uint4 u0 = *(const uint4*)(vbase + coff);
        bf16x8 vf;
        if (shft == 0) {
            vf = u4_as_bf(u0);
        } else {    // shift 5 bf16 elems: out ush_j = src ush_{j+5}
            const uint4 u1 = *(const uint4*)(vbase + coff + 8);
            const unsigned int s2 = u0.z, s3 = u0.w,
                               s4 = u1.x, s5 = u1.y, s6 = u1.z;
            uint4 o;
            o.x = (s2 >> 16) | (s3 << 16);
            o.y = (s3 >> 16) | (s4 << 16);
            o.z = (s4 >> 16) | (s5 << 16);
            o.w = (s5 >> 16) | (s6 << 16);
            vf = u4_as_bf(o);
        }
        const bf16x8 ph = u4_as_bf(*(const uint4*)&pl[kt * 32 + g * 8]);
        const bf16x8 po = u4_as_bf(*(const uint4*)&pl[136 + kt * 32 + g * 8]);
        acc = __builtin_amdgcn_mfma_f32_16x16x32_bf16(vf, ph, acc, 0, 0, 0);
        acc = __builtin_amdgcn_mfma_f32_16x16x32_bf16(vf, po, acc, 0, 0, 0);
    }

    // ---- epilogue: normalize, store O^T[d][px] ----
    const float inv = 1.f / s;
    const int pix = seg * 16 + nn;
    #pragma unroll
    for (int r = 0; r < 4; ++r)
        a_t[(size_t)(h * HD + g4 + r) * NPIX + pix] = acc[r] * inv;
}

// ---------------------------------------------------------------------------
// K3: 1x1 projection, single-pass GEMM (unchanged, R0-proven).
// ---------------------------------------------------------------------------
__global__ __launch_bounds__(256) void proj_kernel(
    const float* __restrict__ a_t,      // [CH][NPIX]
    const float* __restrict__ pw,       // [128][128] ([o][c])
    const float* __restrict__ pb,       // [128]
    float* __restrict__ out)            // [128][NPIX]
{
    __shared__ float at[CH][36];        // 18,432 B

    const int tid = threadIdx.x;
    const int px0 = blockIdx.x * 32;

    #pragma unroll
    for (int it = 0; it < 4; ++it) {
        const int idx = it * 256 + tid;     // 0..1023
        const int c   = idx >> 3;           // 0..127
        const int p4  = (idx & 7) * 4;      // 0,4,..,28
        *(float4*)&at[c][p4] =
            *(const float4*)(a_t + (size_t)c * NPIX + px0 + p4);
    }
    __syncthreads();

    const int og = tid >> 3;                // 0..31 -> 4 o each
    const int o0 = og * 4;
    const int p0 = (tid & 7) * 4;           // 0..28

    float acc[4][4];
    #pragma unroll
    for (int i = 0; i < 4; ++i) {
        const float b = pb[o0 + i];
        #pragma unroll
        for (int jj = 0; jj < 4; ++jj) acc[i][jj] = b;
    }

    #pragma unroll 2
    for (int c0 = 0; c0 < CH; c0 += 4) {
        float4 wv[4];
        #pragma unroll
        for (int i = 0; i < 4; ++i)
            wv[i] = *(const float4*)(pw + (size_t)(o0 + i) * CH + c0);
        float4 av[4];
        #pragma unroll
        for (int k = 0; k < 4; ++k)
            av[k] = *(const float4*)&at[c0 + k][p0];
        #pragma unroll
        for (int i = 0; i < 4; ++i) {
            acc[i][0] += wv[i].x * av[0].x; acc[i][1] += wv[i].x * av[0].y;
            acc[i][2] += wv[i].x * av[0].z; acc[i][3] += wv[i].x * av[0].w;
            acc[i][0] += wv[i].y * av[1].x; acc[i][1] += wv[i].y * av[1].y;
            acc[i][2] += wv[i].y * av[1].z; acc[i][3] += wv[i].y * av[1].w;
            acc[i][0] += wv[i].z * av[2].x; acc[i][1] += wv[i].z * av[2].y;
            acc[i][2] += wv[i].z * av[2].z; acc[i][3] += wv[i].z * av[2].w;
            acc[i][0] += wv[i].w * av[3].x; acc[i][1] += wv[i].w * av[3].y;
            acc[i][2] += wv[i].w * av[3].z; acc[i][3] += wv[i].w * av[3].w;
        }
    }

    #pragma unroll
    for (int i = 0; i < 4; ++i)
        *(float4*)(out + (size_t)(o0 + i) * NPIX + px0 + p0)
            = make_float4(acc[i][0], acc[i][1], acc[i][2], acc[i][3]);
}

// ---------------------------------------------------------------------------
extern "C" void kernel_launch(void* const* d_in, const int* in_sizes, int n_in,
                              void* d_out, int out_size, void* d_ws, size_t ws_size,
                              hipStream_t stream)
{
    const float* x      = (const float*)d_in[0];
    const float* qkv_w  = (const float*)d_in[1];
    const float* qkv_b  = (const float*)d_in[2];
    const float* proj_w = (const float*)d_in[3];
    const float* proj_b = (const float*)d_in[4];
    float* out = (float*)d_out;

    // ws: [vt_pm 0.59 MB][q_pm 2.36 MB][k_pm 0.59 MB][a_t 4.72 MB]
    // vt_pm FIRST so attn's small right-edge overreads land in q_pm (finite).
    unsigned short* vt_pm = (unsigned short*)d_ws;             // [CH][NEPIX]
    unsigned short* q_pm  = vt_pm + (size_t)CH * NEPIX;        // [NPIX][CH]
    unsigned short* k_pm  = q_pm + (size_t)NPIX * CH;          // [NEPIX][CH]
    float*          a_t   = (float*)(k_pm + (size_t)NEPIX * CH);

    conv_kernel<<<384, 256, 0, stream>>>(x, qkv_w, qkv_b, q_pm, k_pm, vt_pm);
    attn_kernel<<<576, 512, 0, stream>>>(q_pm, k_pm, vt_pm, a_t);
    proj_kernel<<<288, 256, 0, stream>>>(a_t, proj_w, proj_b, out);
}

// Round 5
// 92.880 us; speedup vs baseline: 1.2544x; 1.0328x over previous
//
#include <hip/hip_runtime.h>
#include <hip/hip_bf16.h>

// Problem constants (B=1). All inputs/outputs are float32.
#define HH   96
#define WW   96
#define NPIX 9216          // 96*96
#define CH   128
#define NH   8
#define HD   16
#define KS   8

#define NEPIX   2304       // 48*48 even-even grid (k/v only ever read there)
#define QTP  136           // conv q-tile pitch (ch)
#define KVTP 264           // conv kv-tile pitch (k 0..127, v 128..255, pad)
#define XP2  61            // conv input-slab pitch (floats/ch: 3 rows x 20 + 1)
#define PP2  72            // attn P-lds pitch (ush): 64 k-slots + 8 pad

typedef __attribute__((ext_vector_type(8))) short bf16x8;
typedef __attribute__((ext_vector_type(4))) float f32x4;

__device__ __forceinline__ unsigned short f2bf(float f) {
    __hip_bfloat16 b = __float2bfloat16(f);
    union { __hip_bfloat16 b; unsigned short u; } cv; cv.b = b; return cv.u;
}
__device__ __forceinline__ bf16x8 u4_as_bf(uint4 u) {
    union { uint4 u; bf16x8 b; } cv; cv.u = u; return cv.b;
}

// ---------------------------------------------------------------------------
// K1: depthwise 3x3 conv, 12-px strips (was 24): grid 768 = 96 rows x 8,
// LDS 37.7 KB -> 4 resident blocks/CU (2x occupancy, 1/2 block latency).
// q at ALL pixels -> q_pm [NPIX][CH]; k at even-even -> k_pm [NEPIX][CH];
// v at even-even in MFMA-FRAGMENT TILES -> vt_f[h][er48][ecc7][d16][8] bf16
// (chunk ecc=6 zero-filled: attn's masked funnel reads must see finite).
// Per-output conv math identical to the proven kernel.
// ---------------------------------------------------------------------------
__global__ __launch_bounds__(256) void conv_kernel(
    const float* __restrict__ x,        // [128][96][96]
    const float* __restrict__ w,        // [384][1][3][3]
    const float* __restrict__ bias,     // [384]
    unsigned short* __restrict__ q_pm,  // [NPIX][CH] bf16
    unsigned short* __restrict__ k_pm,  // [NEPIX][CH] bf16
    unsigned short* __restrict__ vt_f)  // [8][48][7][16][8] bf16
{
    __shared__ float ldsx[128 * XP2];               // 31,232 B
    __shared__ unsigned short qt [12 * QTP];        // 3,264 B
    __shared__ unsigned short kvt[ 6 * KVTP];       // 3,168 B

    const int row = blockIdx.x >> 3;    // 0..95
    const int q8  = blockIdx.x & 7;     // 0..7
    const int j0q = q8 * 12;
    const int tid = threadIdx.x;
    const int g   = tid >> 1;           // 0..127 input channel / group
    const int sh  = tid & 1;            // 0/1 -> 6 px each
    const bool kvrow = (row & 1) == 0;  // block-uniform

    // ---- stage x[c][row-1..row+1][j0q-4..j0q+15] -> LDS (1920 float4) ----
    #pragma unroll
    for (int it = 0; it < 8; ++it) {
        const int t = it * 256 + tid;
        if (t < 1920) {
            const int r   = t / 640;
            const int rem = t - r * 640;
            const int c   = rem / 5;
            const int s4  = rem - c * 5;        // 0..4
            const int rg  = row + r - 1;
            const int jj  = j0q - 4 + s4 * 4;   // 4-aligned; fully in or out
            float4 v = make_float4(0.f, 0.f, 0.f, 0.f);
            if (rg >= 0 && rg < HH && jj >= 0 && jj < WW)
                v = *(const float4*)(x + (size_t)c * NPIX + rg * WW + jj);
            *(float4*)&ldsx[c * XP2 + r * 20 + s4 * 4] = v;
        }
    }
    __syncthreads();

    // ---- per-thread window: rel col = 3 + sh*6 + m ----
    float xr[3][8];
    {
        const float* xg_l = &ldsx[g * XP2 + 3 + sh * 6];
        #pragma unroll
        for (int dr = 0; dr < 3; ++dr)
            #pragma unroll
            for (int m = 0; m < 8; ++m)
                xr[dr][m] = xg_l[dr * 20 + m];
    }

    #pragma unroll
    for (int dt = 0; dt < 3; ++dt) {
        const int o = 3 * g + dt;       // conv out-channel (group g)
        const int t = o >> 7;           // 0=q, 1=k, 2=v
        const int c = o & 127;
        float w9[9];
        #pragma unroll
        for (int k = 0; k < 9; ++k) w9[k] = w[o * 9 + k];
        const float b = bias[o];

        if (t == 0) {
            #pragma unroll
            for (int px = 0; px < 6; ++px) {
                float acc = b;
                #pragma unroll
                for (int kh = 0; kh < 3; ++kh)
                    #pragma unroll
                    for (int kw = 0; kw < 3; ++kw)
                        acc += xr[kh][px + kw] * w9[kh * 3 + kw];
                qt[(sh * 6 + px) * QTP + c] = f2bf(acc);
            }
        } else if (kvrow) {
            #pragma unroll
            for (int pe = 0; pe < 3; ++pe) {        // even px only
                const int px = pe * 2;
                float acc = b;
                #pragma unroll
                for (int kh = 0; kh < 3; ++kh)
                    #pragma unroll
                    for (int kw = 0; kw < 3; ++kw)
                        acc += xr[kh][px + kw] * w9[kh * 3 + kw];
                kvt[(sh * 3 + pe) * KVTP + (t - 1) * CH + c] = f2bf(acc);
            }
        }
    }

    __syncthreads();

    // ---- write out: q 192 u4; kvrow adds k 96 u4 + v 384 u32 (+zfill) ----
    const int er = row >> 1;
    const int b6 = j0q >> 1;            // 0,6,12,..,42 (even)
    const int ntask = kvrow ? ((q8 == 0) ? 800 : 672) : 192;
    #pragma unroll
    for (int it = 0; it < 4; ++it) {
        const int idx = it * 256 + tid;
        if (idx < 192) {
            const int px = idx >> 4;            // 0..11
            const int c8 = (idx & 15) * 8;
            const uint4 v = *(const uint4*)&qt[px * QTP + c8];
            *(uint4*)(q_pm + ((size_t)(row * WW) + j0q + px) * CH + c8) = v;
        } else if (idx < 288 && kvrow) {        // K: 96 uint4
            const int k2  = idx - 192;
            const int epx = k2 >> 4;            // 0..5
            const int c8  = (k2 & 15) * 8;
            const uint4 v = *(const uint4*)&kvt[epx * KVTP + c8];
            *(uint4*)(k_pm + ((size_t)er * 48 + b6 + epx) * CH + c8) = v;
        } else if (idx < 672 && kvrow) {        // V fragment tiles: 384 u32
            const int v2 = idx - 288;           // 0..383
            const int pr = v2 >> 7;             // 0..2 (col pair)
            const int c  = v2 & 127;
            const int colA  = b6 + pr * 2;      // even -> pair in one chunk
            const int chunk = colA >> 3;
            const int off   = colA & 7;
            const unsigned int a0 =
                (unsigned int)kvt[(pr * 2)     * KVTP + CH + c]
                | ((unsigned int)kvt[(pr * 2 + 1) * KVTP + CH + c] << 16);
            *(unsigned int*)(vt_f
                + (((size_t)(c >> 4) * 48 + er) * 7 + chunk) * 128
                + (c & 15) * 8 + off) = a0;
        } else if (idx < ntask) {               // zfill chunk 6: 128 uint4
            const int zf = idx - 672;           // 0..127
            const int hh = zf >> 4;
            const int d  = zf & 15;
            *(uint4*)(vt_f + (((size_t)hh * 48 + er) * 7 + 6) * 128 + d * 8)
                = make_uint4(0u, 0u, 0u, 0u);
        }
    }
}

// ---------------------------------------------------------------------------
// K2: MFMA neighborhood attention (R4 structure, two fixes):
//  (1) V A-fragments now load COALESCED from vt_f tiles (4 cache lines per
//      instr, was a 64-line scatter from vt_pm), funnel-shift by the
//      block-uniform col offset sh5 in {0,5} - R4-proven shifter.
//  (2) P LDS shrunk 71.7 KB -> 18.4 KB: one 64-slot bf16 buffer per
//      (head, px) reused hi-then-lo (per-wave private, order pinned with
//      sched_barrier). Occupancy now VGPR-bound (~24 waves/CU vs 16).
// Grid 576 segs x 512 thr = 8 waves, one per head; NO barriers.
// ---------------------------------------------------------------------------
__global__ __launch_bounds__(512, 4) void attn_kernel(
    const unsigned short* __restrict__ q_pm,    // [NPIX][CH] bf16
    const unsigned short* __restrict__ k_pm,    // [NEPIX][CH] bf16
    const unsigned short* __restrict__ vt_f,    // [8][48][7][16][8] bf16
    float* __restrict__ a_t)                    // [CH][NPIX] fp32
{
    __shared__ unsigned short plds[NH][16 * PP2];   // 18,432 B

    const int seg = blockIdx.x;                 // 0..575
    const int i   = seg / 6;                    // image row
    const int j0  = (seg - i * 6) * 16;
    const int er0 = min(max(i / 2 - 3, 0), 40); // compact window row base
    const int ec0 = min(max(j0 / 2 - 3, 0), 40);// compact window col base
    const int ecs = ec0 >> 3;                   // base chunk 0..4
    const int sh5 = ec0 & 7;                    // 0 or 5 (block-uniform)

    const int tid  = threadIdx.x;
    const int h    = tid >> 6;                  // head = wave
    const int lane = tid & 63;
    const int nn   = lane & 15;                 // px (B/D cols) / d (A rows)
    const int g    = lane >> 4;                 // 0..3
    const int g4   = g * 4;

    const int j   = j0 + nn;
    const int ci0 = min(max(j / 2 - 3, 0), 40) - ec0;   // 0..7 (per px)

    // ---- QK^T: 8x mfma_16x16x32, A=K window row, B=Q ----
    bf16x8 qf = (bf16x8)(short)0;
    if (g < 2)
        qf = u4_as_bf(*(const uint4*)(q_pm + (size_t)(seg * 16 + nn) * CH
                                      + h * HD + g * 8));
    const f32x4 zacc = {0.f, 0.f, 0.f, 0.f};
    f32x4 st[8];
    #pragma unroll
    for (int t = 0; t < 8; ++t) {
        bf16x8 kf = (bf16x8)(short)0;
        if (g < 2) {
            const int ep = (er0 + t) * 48 + min(ec0 + nn, 47);
            kf = u4_as_bf(*(const uint4*)(k_pm + (size_t)ep * CH
                                          + h * HD + g * 8));
        }
        st[t] = __builtin_amdgcn_mfma_f32_16x16x32_bf16(kf, qf, zacc, 0, 0, 0);
    }

    // ---- masked softmax (scale 0.25 = HD^-0.5; invalid cc -> -1e30) ----
    float m = -1e30f;
    #pragma unroll
    for (int t = 0; t < 8; ++t)
        #pragma unroll
        for (int r = 0; r < 4; ++r) {
            const int cc = g4 + r;
            float T = st[t][r] * 0.25f;
            T = ((unsigned)(cc - ci0) < 8u) ? T : -1e30f;
            st[t][r] = T;
            m = fmaxf(m, T);
        }
    m = fmaxf(m, __shfl_xor(m, 16));
    m = fmaxf(m, __shfl_xor(m, 32));

    float s = 0.f;
    #pragma unroll
    for (int t = 0; t < 8; ++t)
        #pragma unroll
        for (int r = 0; r < 4; ++r) {
            const float p = __expf(st[t][r] - m);       // invalid -> 0
            st[t][r] = p;
            s += p;
        }
    s += __shfl_xor(s, 16);
    s += __shfl_xor(s, 32);

    // ---- PV in two 4-row halves; P buffer reused hi-then-lo ----
    unsigned short* pr = &plds[h][nn * PP2];
    f32x4 acc = {0.f, 0.f, 0.f, 0.f};

    #pragma unroll
    for (int hf = 0; hf < 2; ++hf) {
        // pack P-hi for window rows hf*4 .. hf*4+3
        #pragma unroll
        for (int tl = 0; tl < 4; ++tl) {
            const f32x4 P = st[hf * 4 + tl];
            const unsigned short a0 = f2bf(P[0]), a1 = f2bf(P[1]),
                                 a2 = f2bf(P[2]), a3 = f2bf(P[3]);
            *(uint2*)&pr[tl * 16 + g4] =
                make_uint2((unsigned)a0 | ((unsigned)a1 << 16),
                           (unsigned)a2 | ((unsigned)a3 << 16));
        }
        // PV-hi (A kept in regs for the lo pass)
        bf16x8 vfr[2];
        #pragma unroll
        for (int ks = 0; ks < 2; ++ks) {
            const int tl = ks * 2 + (g >> 1);
            const int er = er0 + hf * 4 + tl;
            const int ch = ecs + (g & 1);
            const unsigned short* vb = vt_f
                + ((size_t)(h * 48 + er) * 7 + ch) * 128 + nn * 8;
            const uint4 u0 = *(const uint4*)vb;
            if (sh5 == 0) {
                vfr[ks] = u4_as_bf(u0);
            } else {                    // shift by 5 bf16 elems
                const uint4 u1 = *(const uint4*)(vb + 128);
                uint4 o;
                o.x = (u0.z >> 16) | (u0.w << 16);
                o.y = (u0.w >> 16) | (u1.x << 16);
                o.z = (u1.x >> 16) | (u1.y << 16);
                o.w = (u1.y >> 16) | (u1.z << 16);
                vfr[ks] = u4_as_bf(o);
            }
            const bf16x8 pb =
                u4_as_bf(*(const uint4*)&pr[tl * 16 + (g & 1) * 8]);
            acc = __builtin_amdgcn_mfma_f32_16x16x32_bf16(vfr[ks], pb, acc,
                                                          0, 0, 0);
        }
        __builtin_amdgcn_sched_barrier(0);  // keep lo-writes after hi-reads
        // pack P-lo (overwrites the same slots)
        #pragma unroll
        for (int tl = 0; tl < 4; ++tl) {
            const f32x4 P = st[hf * 4 + tl];
            unsigned short lo[4];
            #pragma unroll
            for (int r = 0; r < 4; ++r) {
                const unsigned short hi = f2bf(P[r]);
                lo[r] = f2bf(P[r] - __uint_as_float((unsigned)hi << 16));
            }
            *(uint2*)&pr[tl * 16 + g4] =
                make_uint2((unsigned)lo[0] | ((unsigned)lo[1] << 16),
                           (unsigned)lo[2] | ((unsigned)lo[3] << 16));
        }
        __builtin_amdgcn_sched_barrier(0);
        // PV-lo
        #pragma unroll
        for (int ks = 0; ks < 2; ++ks) {
            const int tl = ks * 2 + (g >> 1);
            const bf16x8 pb =
                u4_as_bf(*(const uint4*)&pr[tl * 16 + (g & 1) * 8]);
            acc = __builtin_amdgcn_mfma_f32_16x16x32_bf16(vfr[ks], pb, acc,
                                                          0, 0, 0);
        }
        __builtin_amdgcn_sched_barrier(0);
    }

    // ---- epilogue: normalize, store O^T[d][px] ----
    const float inv = 1.f / s;
    const int pix = seg * 16 + nn;
    #pragma unroll
    for (int r = 0; r < 4; ++r)
        a_t[(size_t)(h * HD + g4 + r) * NPIX + pix] = acc[r] * inv;
}

// ---------------------------------------------------------------------------
// K3: 1x1 projection, single-pass GEMM (unchanged, R0-proven).
// ---------------------------------------------------------------------------
__global__ __launch_bounds__(256) void proj_kernel(
    const float* __restrict__ a_t,      // [CH][NPIX]
    const float* __restrict__ pw,       // [128][128] ([o][c])
    const float* __restrict__ pb,       // [128]
    float* __restrict__ out)            // [128][NPIX]
{
    __shared__ float at[CH][36];        // 18,432 B

    const int tid = threadIdx.x;
    const int px0 = blockIdx.x * 32;

    #pragma unroll
    for (int it = 0; it < 4; ++it) {
        const int idx = it * 256 + tid;     // 0..1023
        const int c   = idx >> 3;           // 0..127
        const int p4  = (idx & 7) * 4;      // 0,4,..,28
        *(float4*)&at[c][p4] =
            *(const float4*)(a_t + (size_t)c * NPIX + px0 + p4);
    }
    __syncthreads();

    const int og = tid >> 3;                // 0..31 -> 4 o each
    const int o0 = og * 4;
    const int p0 = (tid & 7) * 4;           // 0..28

    float acc[4][4];
    #pragma unroll
    for (int i = 0; i < 4; ++i) {
        const float b = pb[o0 + i];
        #pragma unroll
        for (int jj = 0; jj < 4; ++jj) acc[i][jj] = b;
    }

    #pragma unroll 2
    for (int c0 = 0; c0 < CH; c0 += 4) {
        float4 wv[4];
        #pragma unroll
        for (int i = 0; i < 4; ++i)
            wv[i] = *(const float4*)(pw + (size_t)(o0 + i) * CH + c0);
        float4 av[4];
        #pragma unroll
        for (int k = 0; k < 4; ++k)
            av[k] = *(const float4*)&at[c0 + k][p0];
        #pragma unroll
        for (int i = 0; i < 4; ++i) {
            acc[i][0] += wv[i].x * av[0].x; acc[i][1] += wv[i].x * av[0].y;
            acc[i][2] += wv[i].x * av[0].z; acc[i][3] += wv[i].x * av[0].w;
            acc[i][0] += wv[i].y * av[1].x; acc[i][1] += wv[i].y * av[1].y;
            acc[i][2] += wv[i].y * av[1].z; acc[i][3] += wv[i].y * av[1].w;
            acc[i][0] += wv[i].z * av[2].x; acc[i][1] += wv[i].z * av[2].y;
            acc[i][2] += wv[i].z * av[2].z; acc[i][3] += wv[i].z * av[2].w;
            acc[i][0] += wv[i].w * av[3].x; acc[i][1] += wv[i].w * av[3].y;
            acc[i][2] += wv[i].w * av[3].z; acc[i][3] += wv[i].w * av[3].w;
        }
    }

    #pragma unroll
    for (int i = 0; i < 4; ++i)
        *(float4*)(out + (size_t)(o0 + i) * NPIX + px0 + p0)
            = make_float4(acc[i][0], acc[i][1], acc[i][2], acc[i][3]);
}

// ---------------------------------------------------------------------------
extern "C" void kernel_launch(void* const* d_in, const int* in_sizes, int n_in,
                              void* d_out, int out_size, void* d_ws, size_t ws_size,
                              hipStream_t stream)
{
    const float* x      = (const float*)d_in[0];
    const float* qkv_w  = (const float*)d_in[1];
    const float* qkv_b  = (const float*)d_in[2];
    const float* proj_w = (const float*)d_in[3];
    const float* proj_b = (const float*)d_in[4];
    float* out = (float*)d_out;

    // ws: [q_pm 2.36 MB][k_pm 0.59 MB][vt_f 0.69 MB][a_t 4.72 MB]
    unsigned short* q_pm = (unsigned short*)d_ws;              // [NPIX][CH]
    unsigned short* k_pm = q_pm + (size_t)NPIX * CH;           // [NEPIX][CH]
    unsigned short* vt_f = k_pm + (size_t)NEPIX * CH;          // [8][48][7][16][8]
    float*          a_t  = (float*)(vt_f + (size_t)8 * 48 * 7 * 128);

    conv_kernel<<<768, 256, 0, stream>>>(x, qkv_w, qkv_b, q_pm, k_pm, vt_f);
    attn_kernel<<<576, 512, 0, stream>>>(q_pm, k_pm, vt_f, a_t);
    proj_kernel<<<288, 256, 0, stream>>>(a_t, proj_w, proj_b, out);
}